// Round 7
// baseline (628.848 us; speedup 1.0000x reference)
//
#include <hip/hip_runtime.h>
#include <hip/hip_bf16.h>

#define BATCH 4096
#define T_LEN 1024
#define HID 32
#define CT 64
#define NCHUNK (T_LEN / CT)
#define L2E 1.4426950408889634f

typedef short bf16x8 __attribute__((ext_vector_type(8)));
typedef float f32x4 __attribute__((ext_vector_type(4)));

// float -> bf16 RNE; also returns the bf16 value re-expanded to f32 (exact)
__device__ __forceinline__ short bf16hi_rne(float f, float* back) {
    unsigned u = __float_as_uint(f);
    unsigned r = (u + 0x7fffu + ((u >> 16) & 1u)) & 0xffff0000u;
    *back = __uint_as_float(r);
    return (short)(r >> 16);
}
__device__ __forceinline__ float fast_rcp(float x)  { return __builtin_amdgcn_rcpf(x); }
__device__ __forceinline__ float fast_exp2(float x) { return __builtin_amdgcn_exp2f(x); }

// Single-wave-per-16-batch GRU: one wave owns ALL 6 gate tiles (r,z,n x 2),
// so the recurrence never leaves the wave: no exchange, no per-step barrier,
// no per-step LDS on the critical path. Slot map j(i)=16*(i>>2)+4rg+(i&3)
// (verified rounds 0-6): n-tile MFMA C-quads are exactly the lane's next-step
// B-fragment slots -> zero-mov feedback. x is read per-quad straight from
// global (dwordx4, prefetched 4 steps ahead); out-projection partials are
// fire-and-forget LDS writes flushed once per 64-step chunk.
// r/z rows prescaled by log2(e), n rows by 2*log2(e):
// sigmoid = rcp(1+exp2(-pre)), tanh = 1 - 2*rcp(1+exp2(pre)).
__global__ void __launch_bounds__(64, 1)
gru_fused4(const float* __restrict__ xg, const float* __restrict__ h0g,
           const float* __restrict__ Wih, const float* __restrict__ Whh,
           const float* __restrict__ bih, const float* __restrict__ bhh,
           const float* __restrict__ Wout, const float* __restrict__ boutp,
           float* __restrict__ outp)
{
    const int l   = threadIdx.x;
    const int rg  = (l >> 4) & 3;
    const int cl  = l & 15;
    const int b0  = blockIdx.x << 4;

    __shared__ float po[4][16][68];   // out-proj partials [rg][cl][t], 16B-aligned rows

    // ---- W_hh fragments: 6 tiles, hi/lo bf16 split, prescaled ----
    bf16x8 WAhi[6], WAlo[6];
#pragma unroll
    for (int m = 0; m < 6; ++m) {
        const float sc = (m < 4) ? L2E : 2.0f * L2E;
#pragma unroll
        for (int i = 0; i < 8; ++i) {
            int j = 16 * (i >> 2) + 4 * rg + (i & 3);
            float wv = Whh[(m * 16 + cl) * HID + j] * sc;
            float hf, d;
            WAhi[m][i] = bf16hi_rne(wv, &hf);
            WAlo[m][i] = bf16hi_rne(wv - hf, &d);
        }
    }
    // ---- per-slot gate constants (slot i <-> hidden j(i)=16*(i>>2)+4rg+(i&3)) ----
    float wr[8], br[8], wz[8], bz[8], wn[8], bn[8], wout8[8];
    f32x4 bN[2];
#pragma unroll
    for (int i = 0; i < 8; ++i) {
        int row = 4 * rg + (i & 3);
        int hi  = i >> 2;
        int gr  = hi * 16 + row;
        int gz  = (2 + hi) * 16 + row;
        int gn  = (4 + hi) * 16 + row;
        wr[i] = L2E * Wih[gr];  br[i] = L2E * (bih[gr] + bhh[gr]);
        wz[i] = L2E * Wih[gz];  bz[i] = L2E * (bih[gz] + bhh[gz]);
        wn[i] = 2.0f * L2E * Wih[gn];  bn[i] = 2.0f * L2E * bih[gn];
        bN[hi][i & 3] = 2.0f * L2E * bhh[gn];
        wout8[i] = Wout[16 * hi + row];
    }
    const float bout = boutp[0];

    // ---- h0 ----
    float h[8];
    bf16x8 Bhi, Blo;
#pragma unroll
    for (int i = 0; i < 8; ++i) {
        int j = 16 * (i >> 2) + 4 * rg + (i & 3);
        float hv = h0g[(size_t)(b0 + cl) * HID + j];
        h[i] = hv;
        float hf;
        Bhi[i] = bf16hi_rne(hv, &hf);
        Blo[i] = (short)(__float_as_uint(hv - hf) >> 16);   // trunc lo
    }

    const float* xrow = xg + (size_t)(b0 + cl) * T_LEN;
    f32x4 xq = *reinterpret_cast<const f32x4*>(xrow);       // t = 0..3

    for (int tc = 0; tc < NCHUNK; ++tc) {
        // flush previous chunk's output partials (single wave: in-order LDS)
        if (tc > 0) {
            int row = l >> 2, seg = l & 3;
#pragma unroll
            for (int q = 0; q < 4; ++q) {
                int t0 = seg * 16 + q * 4;
                f32x4 s = {bout, bout, bout, bout};
#pragma unroll
                for (int g = 0; g < 4; ++g)
                    s += *reinterpret_cast<const f32x4*>(&po[g][row][t0]);
                *reinterpret_cast<f32x4*>(
                    &outp[(size_t)(b0 + row) * T_LEN + (tc - 1) * CT + t0]) = s;
            }
        }

        for (int qt = 0; qt < 16; ++qt) {
            const int Q = tc * 16 + qt;
            // prefetch next quad's x (wraps at end; wrapped value discarded)
            f32x4 xqn = *reinterpret_cast<const f32x4*>(xrow + (((Q + 1) & 255) << 2));
            f32x4 opv;
#pragma unroll
            for (int s = 0; s < 4; ++s) {
                const float xv = xq[s];
                f32x4 iR0, iR1, iZ0, iZ1;
#pragma unroll
                for (int r = 0; r < 4; ++r) {
                    iR0[r] = fmaf(xv, wr[r],     br[r]);
                    iR1[r] = fmaf(xv, wr[4 + r], br[4 + r]);
                    iZ0[r] = fmaf(xv, wz[r],     bz[r]);
                    iZ1[r] = fmaf(xv, wz[4 + r], bz[4 + r]);
                }
                // 6 independent 3-deep MFMA chains (r0,r1,z0,z1,n0,n1)
                f32x4 aR[2], aZ[2], aN[2];
                aR[0] = __builtin_amdgcn_mfma_f32_16x16x32_bf16(WAhi[0], Bhi, iR0,   0, 0, 0);
                aR[1] = __builtin_amdgcn_mfma_f32_16x16x32_bf16(WAhi[1], Bhi, iR1,   0, 0, 0);
                aZ[0] = __builtin_amdgcn_mfma_f32_16x16x32_bf16(WAhi[2], Bhi, iZ0,   0, 0, 0);
                aZ[1] = __builtin_amdgcn_mfma_f32_16x16x32_bf16(WAhi[3], Bhi, iZ1,   0, 0, 0);
                aN[0] = __builtin_amdgcn_mfma_f32_16x16x32_bf16(WAhi[4], Bhi, bN[0], 0, 0, 0);
                aN[1] = __builtin_amdgcn_mfma_f32_16x16x32_bf16(WAhi[5], Bhi, bN[1], 0, 0, 0);
                aR[0] = __builtin_amdgcn_mfma_f32_16x16x32_bf16(WAhi[0], Blo, aR[0], 0, 0, 0);
                aR[1] = __builtin_amdgcn_mfma_f32_16x16x32_bf16(WAhi[1], Blo, aR[1], 0, 0, 0);
                aZ[0] = __builtin_amdgcn_mfma_f32_16x16x32_bf16(WAhi[2], Blo, aZ[0], 0, 0, 0);
                aZ[1] = __builtin_amdgcn_mfma_f32_16x16x32_bf16(WAhi[3], Blo, aZ[1], 0, 0, 0);
                aN[0] = __builtin_amdgcn_mfma_f32_16x16x32_bf16(WAhi[4], Blo, aN[0], 0, 0, 0);
                aN[1] = __builtin_amdgcn_mfma_f32_16x16x32_bf16(WAhi[5], Blo, aN[1], 0, 0, 0);
                aR[0] = __builtin_amdgcn_mfma_f32_16x16x32_bf16(WAlo[0], Bhi, aR[0], 0, 0, 0);
                aR[1] = __builtin_amdgcn_mfma_f32_16x16x32_bf16(WAlo[1], Bhi, aR[1], 0, 0, 0);
                aZ[0] = __builtin_amdgcn_mfma_f32_16x16x32_bf16(WAlo[2], Bhi, aZ[0], 0, 0, 0);
                aZ[1] = __builtin_amdgcn_mfma_f32_16x16x32_bf16(WAlo[3], Bhi, aZ[1], 0, 0, 0);
                aN[0] = __builtin_amdgcn_mfma_f32_16x16x32_bf16(WAlo[4], Bhi, aN[0], 0, 0, 0);
                aN[1] = __builtin_amdgcn_mfma_f32_16x16x32_bf16(WAlo[5], Bhi, aN[1], 0, 0, 0);

                float op = 0.f;
                bf16x8 nBhi, nBlo;
#pragma unroll
                for (int hi = 0; hi < 2; ++hi)
#pragma unroll
                    for (int r = 0; r < 4; ++r) {
                        const int i = hi * 4 + r;
                        float rr = fast_rcp(1.f + fast_exp2(-aR[hi][r]));
                        float zz = fast_rcp(1.f + fast_exp2(-aZ[hi][r]));
                        float np = fmaf(rr, aN[hi][r], fmaf(xv, wn[i], bn[i]));
                        float nn = fmaf(-2.f, fast_rcp(1.f + fast_exp2(np)), 1.f);
                        float hv = fmaf(zz, h[i] - nn, nn);
                        h[i] = hv;
                        op = fmaf(hv, wout8[i], op);
                        float hf;
                        nBhi[i] = bf16hi_rne(hv, &hf);
                        nBlo[i] = (short)(__float_as_uint(hv - hf) >> 16); // trunc lo
                    }
                Bhi = nBhi;
                Blo = nBlo;
                opv[s] = op;
            }
            // fire-and-forget partial (read only at chunk flush)
            *reinterpret_cast<f32x4*>(&po[rg][cl][qt * 4]) = opv;
            xq = xqn;
        }
        __syncthreads();   // single-wave: compiles to waitcnt; orders po for flush
    }

    // final chunk flush
    {
        int row = l >> 2, seg = l & 3;
#pragma unroll
        for (int q = 0; q < 4; ++q) {
            int t0 = seg * 16 + q * 4;
            f32x4 s = {bout, bout, bout, bout};
#pragma unroll
            for (int g = 0; g < 4; ++g)
                s += *reinterpret_cast<const f32x4*>(&po[g][row][t0]);
            *reinterpret_cast<f32x4*>(
                &outp[(size_t)(b0 + row) * T_LEN + (NCHUNK - 1) * CT + t0]) = s;
        }
    }

    // h_last at d_out[B*T + b*32 + j]
#pragma unroll
    for (int i = 0; i < 8; ++i) {
        int j = 16 * (i >> 2) + 4 * rg + (i & 3);
        outp[(size_t)BATCH * T_LEN + (size_t)(b0 + cl) * HID + j] = h[i];
    }
}

extern "C" void kernel_launch(void* const* d_in, const int* in_sizes, int n_in,
                              void* d_out, int out_size, void* d_ws, size_t ws_size,
                              hipStream_t stream) {
    const float* x     = (const float*)d_in[0];
    const float* h0    = (const float*)d_in[1];
    const float* Wih   = (const float*)d_in[2];
    const float* Whh   = (const float*)d_in[3];
    const float* bihv  = (const float*)d_in[4];
    const float* bhhv  = (const float*)d_in[5];
    const float* Woutv = (const float*)d_in[6];
    const float* boutv = (const float*)d_in[7];
    float* out = (float*)d_out;

    gru_fused4<<<dim3(BATCH / 16), dim3(64), 0, stream>>>(
        x, h0, Wih, Whh, bihv, bhhv, Woutv, boutv, out);
}

// Round 8
// 491.456 us; speedup vs baseline: 1.2796x; 1.2796x over previous
//
#include <hip/hip_runtime.h>
#include <hip/hip_bf16.h>

#define BATCH 4096
#define T_LEN 1024
#define HID 32
#define CT 64
#define NCHUNK (T_LEN / CT)
#define L2E 1.4426950408889634f

typedef short bf16x8 __attribute__((ext_vector_type(8)));
typedef float f32x4 __attribute__((ext_vector_type(4)));

// float -> bf16 RNE; also returns the bf16 value re-expanded to f32 (exact)
__device__ __forceinline__ short bf16hi_rne(float f, float* back) {
    unsigned u = __float_as_uint(f);
    unsigned r = (u + 0x7fffu + ((u >> 16) & 1u)) & 0xffff0000u;
    *back = __uint_as_float(r);
    return (short)(r >> 16);
}
__device__ __forceinline__ float fast_rcp(float x)  { return __builtin_amdgcn_rcpf(x); }
__device__ __forceinline__ float fast_exp2(float x) { return __builtin_amdgcn_exp2f(x); }

#define MFMA __builtin_amdgcn_mfma_f32_16x16x32_bf16

// 2-wave gate split + K-split deferred exchange.
// Wave w computes gate tiles {w,2+w,4+w} (r,z,n of hidden half w), owns h_j
// for j = 16w+4rg+r. A is split by k-half: A_own (k in own half, slots 0-3,
// slots 4-7 ZERO) and A_oth (k in other half, slots 0-3, rest zero). Any
// slot<->k bijection applied to both operands of one MFMA is valid, so:
//   own-K MFMAs: B = pk (own fresh pack; elements 4-7 = lo values, finite,
//                 killed by A's zero slots) -> no exchange dependency;
//   oth-K MFMAs: B = R (exchange read), deferred to after 9 own MFMAs so the
//                 ds_read latency is covered.
// Rotated loop: MFMA(t) -> act(t) -> pack -> ds_write -> barrier -> ds_read
// (consumed at t+1). One barrier/step, parity double-buffer (parity = s&1,
// compile-time in the unrolled quad). r/z rows prescaled by log2(e), n rows
// by 2*log2(e): sigmoid = rcp(1+exp2(-pre)), tanh = 1-2*rcp(1+exp2(pre)).
__global__ void __launch_bounds__(128, 1)
gru_fused5(const float* __restrict__ xg, const float* __restrict__ h0g,
           const float* __restrict__ Wih, const float* __restrict__ Whh,
           const float* __restrict__ bih, const float* __restrict__ bhh,
           const float* __restrict__ Wout, const float* __restrict__ boutp,
           float* __restrict__ outp)
{
    const int tid = threadIdx.x;
    const int w   = tid >> 6;
    const int l   = tid & 63;
    const int rg  = (l >> 4) & 3;
    const int cl  = l & 15;
    const int b0  = blockIdx.x << 4;

    __shared__ float xbuf[16][68];
    __shared__ float po[8][16][68];                      // out-proj partials
    __shared__ __align__(16) short exch[2][2][64 * 8];   // [parity][wave][lane*8]

    // ---- A fragments: own-K / oth-K, hi/lo bf16 split, prescaled ----
    bf16x8 AownHi[3], AownLo[3], AothHi[3], AothLo[3];
#pragma unroll
    for (int q = 0; q < 3; ++q) {
        const int m = 2 * q + w;
        const float sc = (q < 2) ? L2E : 2.0f * L2E;
#pragma unroll
        for (int i = 0; i < 8; ++i) {
            if (i < 4) {
                float hf, d;
                float wv = Whh[(m * 16 + cl) * HID + 16 * w + 4 * rg + i] * sc;
                AownHi[q][i] = bf16hi_rne(wv, &hf);
                AownLo[q][i] = bf16hi_rne(wv - hf, &d);
                float wv2 = Whh[(m * 16 + cl) * HID + 16 * (1 - w) + 4 * rg + i] * sc;
                AothHi[q][i] = bf16hi_rne(wv2, &hf);
                AothLo[q][i] = bf16hi_rne(wv2 - hf, &d);
            } else {   // zero slots: kill the garbage elements of the B views
                AownHi[q][i] = 0; AownLo[q][i] = 0;
                AothHi[q][i] = 0; AothLo[q][i] = 0;
            }
        }
    }
    // ---- gate constants (C row = 4rg + r within tile) ----
    float wrz[8], brz[8], win[4], bin[4], wout4[4];
    f32x4 bN;
#pragma unroll
    for (int q = 0; q < 2; ++q)
#pragma unroll
        for (int r = 0; r < 4; ++r) {
            int g = (2 * q + w) * 16 + 4 * rg + r;
            wrz[q * 4 + r] = L2E * Wih[g];
            brz[q * 4 + r] = L2E * (bih[g] + bhh[g]);
        }
#pragma unroll
    for (int r = 0; r < 4; ++r) {
        int g = (4 + w) * 16 + 4 * rg + r;
        win[r]   = 2.0f * L2E * Wih[g];
        bin[r]   = 2.0f * L2E * bih[g];
        bN[r]    = 2.0f * L2E * bhh[g];
        wout4[r] = Wout[16 * w + 4 * rg + r];
    }
    const float bout = boutp[0];

    // ---- h0: own pack pk = [hi0-3, lo0-3]; other half R likewise ----
    float h[4];
    bf16x8 pk, R;
#pragma unroll
    for (int r = 0; r < 4; ++r) {
        float hv = h0g[(size_t)(b0 + cl) * HID + 16 * w + 4 * rg + r];
        h[r] = hv;
        float hf;
        pk[r]     = bf16hi_rne(hv, &hf);
        pk[4 + r] = (short)(__float_as_uint(hv - hf) >> 16);
        float ov = h0g[(size_t)(b0 + cl) * HID + 16 * (1 - w) + 4 * rg + r];
        R[r]     = bf16hi_rne(ov, &hf);
        R[4 + r] = (short)(__float_as_uint(ov - hf) >> 16);
    }

    short* const exMy       = &exch[0][w][l * 8];       // + (s&1)*1024 shorts
    const short* const exOt = &exch[0][1 - w][l * 8];

    for (int tc = 0; tc < NCHUNK; ++tc) {
        if (tc > 0) {  // flush previous chunk (po writes ordered by step barriers)
            int row = tid >> 3, t0 = (tid & 7) * 8;
            f32x4 s0 = {bout, bout, bout, bout}, s1 = s0;
#pragma unroll
            for (int g = 0; g < 8; ++g) {
                s0 += *reinterpret_cast<const f32x4*>(&po[g][row][t0]);
                s1 += *reinterpret_cast<const f32x4*>(&po[g][row][t0 + 4]);
            }
            float* dst = &outp[(size_t)(b0 + row) * T_LEN + (tc - 1) * CT + t0];
            *reinterpret_cast<f32x4*>(dst)     = s0;
            *reinterpret_cast<f32x4*>(dst + 4) = s1;
        }
#pragma unroll
        for (int q = 0; q < 8; ++q)
            xbuf[w * 8 + q][l] = xg[(size_t)(b0 + w * 8 + q) * T_LEN + tc * CT + l];
        __syncthreads();
        f32x4 xq = *reinterpret_cast<const f32x4*>(&xbuf[cl][0]);

        for (int qt = 0; qt < 16; ++qt) {
            f32x4 xqn = *reinterpret_cast<const f32x4*>(&xbuf[cl][((qt + 1) & 15) * 4]);
            f32x4 opv;
#pragma unroll
            for (int s = 0; s < 4; ++s) {
                const float xv = xq[s];
                // lo-views: elements 0-3 = lo (hi) values, 4-7 zero-weighted garbage
                bf16x8 pkLo = __builtin_shufflevector(pk, pk, 4, 5, 6, 7, 0, 1, 2, 3);
                bf16x8 RLo  = __builtin_shufflevector(R,  R,  4, 5, 6, 7, 0, 1, 2, 3);
                f32x4 iR, iZ;
#pragma unroll
                for (int r = 0; r < 4; ++r) {
                    iR[r] = fmaf(xv, wrz[r],     brz[r]);
                    iZ[r] = fmaf(xv, wrz[4 + r], brz[4 + r]);
                }
                // 9 own-K MFMAs: no dependency on this step's exchange
                f32x4 aR, aZ, aN;
                aR = MFMA(AownHi[0], pk,   iR, 0, 0, 0);
                aZ = MFMA(AownHi[1], pk,   iZ, 0, 0, 0);
                aN = MFMA(AownHi[2], pk,   bN, 0, 0, 0);
                aR = MFMA(AownLo[0], pk,   aR, 0, 0, 0);
                aZ = MFMA(AownLo[1], pk,   aZ, 0, 0, 0);
                aN = MFMA(AownLo[2], pk,   aN, 0, 0, 0);
                aR = MFMA(AownHi[0], pkLo, aR, 0, 0, 0);
                aZ = MFMA(AownHi[1], pkLo, aZ, 0, 0, 0);
                aN = MFMA(AownHi[2], pkLo, aN, 0, 0, 0);
                // 9 oth-K MFMAs: first use of R -> ds_read latency covered above
                aR = MFMA(AothHi[0], R,    aR, 0, 0, 0);
                aZ = MFMA(AothHi[1], R,    aZ, 0, 0, 0);
                aN = MFMA(AothHi[2], R,    aN, 0, 0, 0);
                aR = MFMA(AothLo[0], R,    aR, 0, 0, 0);
                aZ = MFMA(AothLo[1], R,    aZ, 0, 0, 0);
                aN = MFMA(AothLo[2], R,    aN, 0, 0, 0);
                aR = MFMA(AothHi[0], RLo,  aR, 0, 0, 0);
                aZ = MFMA(AothHi[1], RLo,  aZ, 0, 0, 0);
                aN = MFMA(AothHi[2], RLo,  aN, 0, 0, 0);

                bf16x8 npk;
                float op = 0.f;
#pragma unroll
                for (int r = 0; r < 4; ++r) {
                    float rr = fast_rcp(1.f + fast_exp2(-aR[r]));
                    float zz = fast_rcp(1.f + fast_exp2(-aZ[r]));
                    float np = fmaf(rr, aN[r], fmaf(xv, win[r], bin[r]));
                    float nn = fmaf(-2.f, fast_rcp(1.f + fast_exp2(np)), 1.f);
                    float hv = fmaf(zz, h[r] - nn, nn);
                    h[r] = hv;
                    op = fmaf(hv, wout4[r], op);
                    float hf;
                    npk[r]     = bf16hi_rne(hv, &hf);
                    npk[4 + r] = (short)(__float_as_uint(hv - hf) >> 16); // trunc lo
                }
                pk = npk;
                opv[s] = op;
                *reinterpret_cast<bf16x8*>(exMy + (s & 1) * 1024) = pk;
                if (s == 3)  // po write must precede this step's barrier
                    *reinterpret_cast<f32x4*>(&po[w * 4 + rg][cl][qt * 4]) = opv;
                __syncthreads();
                R = *reinterpret_cast<const bf16x8*>(exOt + (s & 1) * 1024);
            }
            xq = xqn;
        }
    }

    // final chunk flush
    {
        int row = tid >> 3, t0 = (tid & 7) * 8;
        f32x4 s0 = {bout, bout, bout, bout}, s1 = s0;
#pragma unroll
        for (int g = 0; g < 8; ++g) {
            s0 += *reinterpret_cast<const f32x4*>(&po[g][row][t0]);
            s1 += *reinterpret_cast<const f32x4*>(&po[g][row][t0 + 4]);
        }
        float* dst = &outp[(size_t)(b0 + row) * T_LEN + (NCHUNK - 1) * CT + t0];
        *reinterpret_cast<f32x4*>(dst)     = s0;
        *reinterpret_cast<f32x4*>(dst + 4) = s1;
    }

    // h_last at d_out[B*T + b*32 + j] (own half)
#pragma unroll
    for (int r = 0; r < 4; ++r)
        outp[(size_t)BATCH * T_LEN + (size_t)(b0 + cl) * HID + 16 * w + 4 * rg + r] = h[r];
}

extern "C" void kernel_launch(void* const* d_in, const int* in_sizes, int n_in,
                              void* d_out, int out_size, void* d_ws, size_t ws_size,
                              hipStream_t stream) {
    const float* x     = (const float*)d_in[0];
    const float* h0    = (const float*)d_in[1];
    const float* Wih   = (const float*)d_in[2];
    const float* Whh   = (const float*)d_in[3];
    const float* bihv  = (const float*)d_in[4];
    const float* bhhv  = (const float*)d_in[5];
    const float* Woutv = (const float*)d_in[6];
    const float* boutv = (const float*)d_in[7];
    float* out = (float*)d_out;

    gru_fused5<<<dim3(BATCH / 16), dim3(128), 0, stream>>>(
        x, h0, Wih, Whh, bihv, bhhv, Woutv, boutv, out);
}

// Round 9
// 400.286 us; speedup vs baseline: 1.5710x; 1.2278x over previous
//
#include <hip/hip_runtime.h>
#include <hip/hip_bf16.h>

#define BATCH 4096
#define T_LEN 1024
#define HID 32
#define CT 64
#define NCHUNK (T_LEN / CT)
#define L2E 1.4426950408889634f

typedef short bf16x8 __attribute__((ext_vector_type(8)));
typedef short short4v __attribute__((ext_vector_type(4)));
typedef float f32x4 __attribute__((ext_vector_type(4)));

// float -> bf16 RNE; also returns the bf16 value re-expanded to f32 (exact)
__device__ __forceinline__ short bf16hi_rne(float f, float* back) {
    unsigned u = __float_as_uint(f);
    unsigned r = (u + 0x7fffu + ((u >> 16) & 1u)) & 0xffff0000u;
    *back = __uint_as_float(r);
    return (short)(r >> 16);
}
__device__ __forceinline__ float fast_rcp(float x)  { return __builtin_amdgcn_rcpf(x); }
__device__ __forceinline__ float fast_exp2(float x) { return __builtin_amdgcn_exp2f(x); }

#define MFMA __builtin_amdgcn_mfma_f32_16x16x32_bf16

// 4-wave activation split with duplicated MFMA.
// Wave v = (half = v&1, sub = v>>1). Waves (half,0) and (half,1) both compute
// gate tiles {half, 2+half, 4+half} (12 MFMAs each, K split in halves with
// combined [Whi,Whi]/[Wlo,0] fragments vs B packed [hi,hi,lo,lo]x2), but each
// activates only 2 hidden units per lane: j = 16*half + 4*rg + 2*sub + {0,1}.
// A-row permutation phi(cl) = 4*(cl>>2) + 2*sub + (cl&1) places each wave's
// 2 target gates at C rows 4rg+0/1 -> compile-time indices, no branches.
// Exchange: each wave ds_write_b64's its 2 h's (hi,hi,lo,lo); every wave
// ds_read_b128's both halves. One barrier/step, parity double-buffer
// (parity = s&1, compile-time in the unrolled 4-step quad).
// r/z rows prescaled by log2(e), n rows by 2*log2(e):
// sigmoid = rcp(1+exp2(-pre)), tanh = 1 - 2*rcp(1+exp2(pre)).
__global__ void __launch_bounds__(256, 1)
gru_fused6(const float* __restrict__ xg, const float* __restrict__ h0g,
           const float* __restrict__ Wih, const float* __restrict__ Whh,
           const float* __restrict__ bih, const float* __restrict__ bhh,
           const float* __restrict__ Wout, const float* __restrict__ boutp,
           float* __restrict__ outp)
{
    const int tid  = threadIdx.x;
    const int v    = tid >> 6;       // wave 0..3
    const int half = v & 1;
    const int sub  = v >> 1;
    const int l    = tid & 63;
    const int rg   = (l >> 4) & 3;
    const int cl   = l & 15;
    const int b0   = blockIdx.x << 4;

    __shared__ float xbuf[16][68];
    __shared__ float po[16][16][68];                    // out-proj partials [wave*4+rg][cl][t]
    __shared__ __align__(16) short ex[2][2][4][16][8];  // [par][half][rg][cl][slot]
    const int PAR = 2 * 4 * 16 * 8;                     // shorts per parity buffer

    // slot maps: B slots = [hi(k0),hi(k1),lo(k0),lo(k1),hi(k2),hi(k3),lo(k2),lo(k3)]
    // shi(qs) = qs<2 ? qs : qs+2 ; slo(qs) = qs<2 ? qs+2 : qs+4
    // ---- A fragments: per tile q, per k-half kh ----
    bf16x8 A1[3][2], A2[3][2];
    const int phicl = 4 * (cl >> 2) + 2 * sub + (cl & 1);   // permuted gate row in tile
#pragma unroll
    for (int q = 0; q < 3; ++q) {
        const int m = 2 * q + half;
        const float sc = (q < 2) ? L2E : 2.0f * L2E;
        const int grow = m * 16 + phicl;
#pragma unroll
        for (int kh = 0; kh < 2; ++kh)
#pragma unroll
            for (int qs = 0; qs < 4; ++qs) {
                float wv = Whh[grow * HID + 16 * kh + 4 * rg + qs] * sc;
                float hf, d;
                short hi = bf16hi_rne(wv, &hf);
                short lo = bf16hi_rne(wv - hf, &d);
                int shi = (qs < 2) ? qs : qs + 2;
                int slo = (qs < 2) ? qs + 2 : qs + 4;
                A1[q][kh][shi] = hi;  A1[q][kh][slo] = hi;
                A2[q][kh][shi] = lo;  A2[q][kh][slo] = 0;
            }
    }
    // ---- activation constants (C rows u'=0..3 hold gate 4rg+2sub+(u'&1)) ----
    float wr4[4], br4[4], wz4[4], bz4[4], wn2[2], bn2[2], wo2[2];
    f32x4 bN;
#pragma unroll
    for (int u = 0; u < 4; ++u) {
        int rrow = 4 * rg + 2 * sub + (u & 1);
        int gr = half * 16 + rrow;
        int gz = (2 + half) * 16 + rrow;
        int gn = (4 + half) * 16 + rrow;
        wr4[u] = L2E * Wih[gr];  br4[u] = L2E * (bih[gr] + bhh[gr]);
        wz4[u] = L2E * Wih[gz];  bz4[u] = L2E * (bih[gz] + bhh[gz]);
        bN[u]  = 2.0f * L2E * bhh[gn];
    }
#pragma unroll
    for (int u = 0; u < 2; ++u) {
        int rrow = 4 * rg + 2 * sub + u;
        int gn = (4 + half) * 16 + rrow;
        wn2[u] = 2.0f * L2E * Wih[gn];
        bn2[u] = 2.0f * L2E * bih[gn];
        wo2[u] = Wout[half * 16 + rrow];
    }
    const float bout = boutp[0];

    // ---- h state (2 own units) + initial B operands from h0 ----
    float h2[2];
#pragma unroll
    for (int u = 0; u < 2; ++u)
        h2[u] = h0g[(size_t)(b0 + cl) * HID + 16 * half + 4 * rg + 2 * sub + u];
    bf16x8 B0, B1;
#pragma unroll
    for (int qs = 0; qs < 4; ++qs) {
        int shi = (qs < 2) ? qs : qs + 2;
        int slo = (qs < 2) ? qs + 2 : qs + 4;
        float hv0 = h0g[(size_t)(b0 + cl) * HID + 4 * rg + qs];
        float hf;
        B0[shi] = bf16hi_rne(hv0, &hf);
        B0[slo] = (short)(__float_as_uint(hv0 - hf) >> 16);
        float hv1 = h0g[(size_t)(b0 + cl) * HID + 16 + 4 * rg + qs];
        B1[shi] = bf16hi_rne(hv1, &hf);
        B1[slo] = (short)(__float_as_uint(hv1 - hf) >> 16);
    }

    short* const exW        = &ex[0][half][rg][cl][sub * 4];  // + (s&1)*PAR
    const short* const exR0 = &ex[0][0][rg][cl][0];
    const short* const exR1 = &ex[0][1][rg][cl][0];

    for (int tc = 0; tc < NCHUNK; ++tc) {
        if (tc > 0) {   // flush previous chunk (po writes ordered by step barriers)
            int row = tid >> 4, seg = tid & 15;
            f32x4 sacc = {bout, bout, bout, bout};
#pragma unroll
            for (int g = 0; g < 16; ++g)
                sacc += *reinterpret_cast<const f32x4*>(&po[g][row][seg * 4]);
            *reinterpret_cast<f32x4*>(
                &outp[(size_t)(b0 + row) * T_LEN + (tc - 1) * CT + seg * 4]) = sacc;
        }
        {   // stage x chunk: 256 threads x f32x4 = 1024 floats
            int row = tid >> 4, seg = tid & 15;
            *reinterpret_cast<f32x4*>(&xbuf[row][seg * 4]) =
                *reinterpret_cast<const f32x4*>(
                    &xg[(size_t)(b0 + row) * T_LEN + tc * CT + seg * 4]);
        }
        __syncthreads();
        f32x4 xq = *reinterpret_cast<const f32x4*>(&xbuf[cl][0]);

        for (int qt = 0; qt < 16; ++qt) {
            f32x4 xqn = *reinterpret_cast<const f32x4*>(&xbuf[cl][((qt + 1) & 15) * 4]);
            f32x4 opv;
#pragma unroll
            for (int s = 0; s < 4; ++s) {
                const float xv = xq[s];
                f32x4 iR, iZ;
#pragma unroll
                for (int u = 0; u < 4; ++u) {
                    iR[u] = fmaf(xv, wr4[u], br4[u]);
                    iZ[u] = fmaf(xv, wz4[u], bz4[u]);
                }
                f32x4 aR, aZ, aN;
                aR = MFMA(A1[0][0], B0, iR, 0, 0, 0);
                aZ = MFMA(A1[1][0], B0, iZ, 0, 0, 0);
                aN = MFMA(A1[2][0], B0, bN, 0, 0, 0);
                aR = MFMA(A2[0][0], B0, aR, 0, 0, 0);
                aZ = MFMA(A2[1][0], B0, aZ, 0, 0, 0);
                aN = MFMA(A2[2][0], B0, aN, 0, 0, 0);
                aR = MFMA(A1[0][1], B1, aR, 0, 0, 0);
                aZ = MFMA(A1[1][1], B1, aZ, 0, 0, 0);
                aN = MFMA(A1[2][1], B1, aN, 0, 0, 0);
                aR = MFMA(A2[0][1], B1, aR, 0, 0, 0);
                aZ = MFMA(A2[1][1], B1, aZ, 0, 0, 0);
                aN = MFMA(A2[2][1], B1, aN, 0, 0, 0);

                float op = 0.f;
                short4v pkv;
#pragma unroll
                for (int u = 0; u < 2; ++u) {
                    float rr = fast_rcp(1.f + fast_exp2(-aR[u]));
                    float zz = fast_rcp(1.f + fast_exp2(-aZ[u]));
                    float np = fmaf(rr, aN[u], fmaf(xv, wn2[u], bn2[u]));
                    float nn = fmaf(-2.f, fast_rcp(1.f + fast_exp2(np)), 1.f);
                    float hv = fmaf(zz, h2[u] - nn, nn);
                    h2[u] = hv;
                    op = fmaf(hv, wo2[u], op);
                    float hf;
                    pkv[u]     = bf16hi_rne(hv, &hf);
                    pkv[2 + u] = (short)(__float_as_uint(hv - hf) >> 16);  // trunc lo
                }
                opv[s] = op;
                *reinterpret_cast<short4v*>(exW + (s & 1) * PAR) = pkv;
                if (s == 3)   // po write must precede this step's barrier
                    *reinterpret_cast<f32x4*>(&po[v * 4 + rg][cl][qt * 4]) = opv;
                __syncthreads();
                B0 = *reinterpret_cast<const bf16x8*>(exR0 + (s & 1) * PAR);
                B1 = *reinterpret_cast<const bf16x8*>(exR1 + (s & 1) * PAR);
            }
            xq = xqn;
        }
    }

    // final chunk flush
    {
        int row = tid >> 4, seg = tid & 15;
        f32x4 sacc = {bout, bout, bout, bout};
#pragma unroll
        for (int g = 0; g < 16; ++g)
            sacc += *reinterpret_cast<const f32x4*>(&po[g][row][seg * 4]);
        *reinterpret_cast<f32x4*>(
            &outp[(size_t)(b0 + row) * T_LEN + (NCHUNK - 1) * CT + seg * 4]) = sacc;
    }

    // h_last at d_out[B*T + b*32 + j] (2 own units per lane)
#pragma unroll
    for (int u = 0; u < 2; ++u)
        outp[(size_t)BATCH * T_LEN + (size_t)(b0 + cl) * HID
             + 16 * half + 4 * rg + 2 * sub + u] = h2[u];
}

extern "C" void kernel_launch(void* const* d_in, const int* in_sizes, int n_in,
                              void* d_out, int out_size, void* d_ws, size_t ws_size,
                              hipStream_t stream) {
    const float* x     = (const float*)d_in[0];
    const float* h0    = (const float*)d_in[1];
    const float* Wih   = (const float*)d_in[2];
    const float* Whh   = (const float*)d_in[3];
    const float* bihv  = (const float*)d_in[4];
    const float* bhhv  = (const float*)d_in[5];
    const float* Woutv = (const float*)d_in[6];
    const float* boutv = (const float*)d_in[7];
    float* out = (float*)d_out;

    gru_fused6<<<dim3(BATCH / 16), dim3(256), 0, stream>>>(
        x, h0, Wih, Whh, bihv, bhhv, Woutv, boutv, out);
}

// Round 10
// 389.452 us; speedup vs baseline: 1.6147x; 1.0278x over previous
//
#include <hip/hip_runtime.h>
#include <hip/hip_bf16.h>

#define BATCH 4096
#define T_LEN 1024
#define HID 32
#define CT 64
#define NCHUNK (T_LEN / CT)
#define L2E 1.4426950408889634f

typedef short bf16x8 __attribute__((ext_vector_type(8)));
typedef float f32x4 __attribute__((ext_vector_type(4)));

// float -> bf16 RNE; also returns the bf16 value re-expanded to f32 (exact)
__device__ __forceinline__ short bf16hi_rne(float f, float* back) {
    unsigned u = __float_as_uint(f);
    unsigned r = (u + 0x7fffu + ((u >> 16) & 1u)) & 0xffff0000u;
    *back = __uint_as_float(r);
    return (short)(r >> 16);
}
__device__ __forceinline__ float fast_rcp(float x)  { return __builtin_amdgcn_rcpf(x); }
__device__ __forceinline__ float fast_exp2(float x) { return __builtin_amdgcn_exp2f(x); }

#define MFMA __builtin_amdgcn_mfma_f32_16x16x32_bf16

// 4-wave activation split + 9-MFMA full-K (separate hi/lo exchange planes).
// Wave v = (half=v&1, sub=v>>1). All waves of a half compute gate tiles
// {half,2+half,4+half}; each wave activates 2 hidden units/lane:
// j = 16*half + 4*rg + 2*sub + {0,1}.
// Exchange: h broadcast as TWO bf16 planes ex[par][hi|lo][cl][j] -> B operand
// is identity-k-mapped (lane (rg,cl): slots = h[8rg..8rg+7]), so each gate
// needs exactly 3 MFMAs: Whi*Bhi + Whi*Blo + Wlo*Bhi (3-deep chains, 9 total).
// A-row permutation phi(cl)=4*(cl>>2)+2*sub+(cl&1) puts the wave's 2 target
// gates at C regs 0,1 (compile-time). Write = 2 x b32/wave; read = 2 x b128.
// One barrier/step, parity double-buffer (parity = s&1, compile-time in the
// unrolled quad). r/z rows prescaled by log2(e), n rows by 2*log2(e):
// sigmoid = rcp(1+exp2(-pre)), tanh = 1 - 2*rcp(1+exp2(pre)).
__global__ void __launch_bounds__(256, 1)
gru_fused7(const float* __restrict__ xg, const float* __restrict__ h0g,
           const float* __restrict__ Wih, const float* __restrict__ Whh,
           const float* __restrict__ bih, const float* __restrict__ bhh,
           const float* __restrict__ Wout, const float* __restrict__ boutp,
           float* __restrict__ outp)
{
    const int tid  = threadIdx.x;
    const int v    = tid >> 6;       // wave 0..3
    const int half = v & 1;
    const int sub  = v >> 1;
    const int l    = tid & 63;
    const int rg   = (l >> 4) & 3;
    const int cl   = l & 15;
    const int b0   = blockIdx.x << 4;

    __shared__ float xbuf[16][68];
    __shared__ float po[16][16][68];                 // out-proj partials [wave*4+rg][cl][t]
    __shared__ __align__(16) short ex[2][2][16][40]; // [par][hi|lo][cl][j0..31 +pad]
    const int PAR = 2 * 16 * 40;                     // shorts per parity buffer

    // ---- A fragments: full-K identity map (slot s at lane rg <-> k=8rg+s) ----
    bf16x8 Ahi[3], Alo[3];
    const int phicl = 4 * (cl >> 2) + 2 * sub + (cl & 1);  // permuted gate row
#pragma unroll
    for (int q = 0; q < 3; ++q) {
        const int m = 2 * q + half;
        const float sc = (q < 2) ? L2E : 2.0f * L2E;
#pragma unroll
        for (int s = 0; s < 8; ++s) {
            float wv = Whh[(m * 16 + phicl) * HID + 8 * rg + s] * sc;
            float hf;
            Ahi[q][s] = bf16hi_rne(wv, &hf);
            Alo[q][s] = (short)(__float_as_uint(wv - hf) >> 16);  // trunc lo
        }
    }
    // ---- activation constants (C reg u holds gate 4rg+2sub+(u&1)) ----
    float wr4[4], br4[4], wz4[4], bz4[4], wn2[2], bn2[2], wo2[2];
    f32x4 bN;
#pragma unroll
    for (int u = 0; u < 4; ++u) {
        int rrow = 4 * rg + 2 * sub + (u & 1);
        int gr = half * 16 + rrow;
        int gz = (2 + half) * 16 + rrow;
        int gn = (4 + half) * 16 + rrow;
        wr4[u] = L2E * Wih[gr];  br4[u] = L2E * (bih[gr] + bhh[gr]);
        wz4[u] = L2E * Wih[gz];  bz4[u] = L2E * (bih[gz] + bhh[gz]);
        bN[u]  = 2.0f * L2E * bhh[gn];
    }
#pragma unroll
    for (int u = 0; u < 2; ++u) {
        int rrow = 4 * rg + 2 * sub + u;
        int gn = (4 + half) * 16 + rrow;
        wn2[u] = 2.0f * L2E * Wih[gn];
        bn2[u] = 2.0f * L2E * bih[gn];
        wo2[u] = Wout[half * 16 + rrow];
    }
    const float bout = boutp[0];

    // ---- h state (2 own units) + initial B operands from h0 ----
    float h2[2];
#pragma unroll
    for (int u = 0; u < 2; ++u)
        h2[u] = h0g[(size_t)(b0 + cl) * HID + 16 * half + 4 * rg + 2 * sub + u];
    bf16x8 Bhi, Blo;
#pragma unroll
    for (int s = 0; s < 8; ++s) {
        float hv = h0g[(size_t)(b0 + cl) * HID + 8 * rg + s];
        float hf;
        Bhi[s] = bf16hi_rne(hv, &hf);
        Blo[s] = (short)(__float_as_uint(hv - hf) >> 16);
    }

    short* const exFlat = &ex[0][0][0][0];
    const int j0 = 16 * half + 4 * rg + 2 * sub;       // own units' j (even)
    short* const exWh = exFlat + cl * 40 + j0;          // hi plane write
    short* const exWl = exFlat + (16 + cl) * 40 + j0;   // lo plane write
    const short* const exRh = exFlat + cl * 40 + 8 * rg;        // b128 read
    const short* const exRl = exFlat + (16 + cl) * 40 + 8 * rg; // b128 read

    for (int tc = 0; tc < NCHUNK; ++tc) {
        // flush previous chunk's po (ordered by the per-step barriers)
        if (tc > 0) {
            int row = tid >> 4, seg = tid & 15;
            f32x4 sacc = {bout, bout, bout, bout};
#pragma unroll
            for (int g = 0; g < 16; ++g)
                sacc += *reinterpret_cast<const f32x4*>(&po[g][row][seg * 4]);
            *reinterpret_cast<f32x4*>(
                &outp[(size_t)(b0 + row) * T_LEN + (tc - 1) * CT + seg * 4]) = sacc;
        }
        {   // stage x chunk: 256 threads x f32x4 = 1024 floats
            int row = tid >> 4, seg = tid & 15;
            *reinterpret_cast<f32x4*>(&xbuf[row][seg * 4]) =
                *reinterpret_cast<const f32x4*>(
                    &xg[(size_t)(b0 + row) * T_LEN + tc * CT + seg * 4]);
        }
        __syncthreads();
        f32x4 xq = *reinterpret_cast<const f32x4*>(&xbuf[cl][0]);

        for (int qt = 0; qt < 16; ++qt) {
            f32x4 xqn = *reinterpret_cast<const f32x4*>(&xbuf[cl][((qt + 1) & 15) * 4]);
            f32x4 opv;
#pragma unroll
            for (int s = 0; s < 4; ++s) {
                const float xv = xq[s];
                f32x4 iR, iZ;
#pragma unroll
                for (int u = 0; u < 4; ++u) {
                    iR[u] = fmaf(xv, wr4[u], br4[u]);
                    iZ[u] = fmaf(xv, wz4[u], bz4[u]);
                }
                // 9 MFMAs, 3 chains of depth 3
                f32x4 aR, aZ, aN;
                aR = MFMA(Ahi[0], Bhi, iR, 0, 0, 0);
                aZ = MFMA(Ahi[1], Bhi, iZ, 0, 0, 0);
                aN = MFMA(Ahi[2], Bhi, bN, 0, 0, 0);
                aR = MFMA(Ahi[0], Blo, aR, 0, 0, 0);
                aZ = MFMA(Ahi[1], Blo, aZ, 0, 0, 0);
                aN = MFMA(Ahi[2], Blo, aN, 0, 0, 0);
                aR = MFMA(Alo[0], Bhi, aR, 0, 0, 0);
                aZ = MFMA(Alo[1], Bhi, aZ, 0, 0, 0);
                aN = MFMA(Alo[2], Bhi, aN, 0, 0, 0);

                float op = 0.f;
                unsigned hw = 0, lw = 0;
#pragma unroll
                for (int u = 0; u < 2; ++u) {
                    float rr = fast_rcp(1.f + fast_exp2(-aR[u]));
                    float zz = fast_rcp(1.f + fast_exp2(-aZ[u]));
                    float np = fmaf(rr, aN[u], fmaf(xv, wn2[u], bn2[u]));
                    float nn = fmaf(-2.f, fast_rcp(1.f + fast_exp2(np)), 1.f);
                    float hv = fmaf(zz, h2[u] - nn, nn);
                    h2[u] = hv;
                    op = fmaf(hv, wo2[u], op);
                    float hf;
                    unsigned hu = (unsigned)(unsigned short)bf16hi_rne(hv, &hf);
                    unsigned lu = (__float_as_uint(hv - hf) >> 16);      // trunc lo
                    hw |= hu << (16 * u);
                    lw |= lu << (16 * u);
                }
                opv[s] = op;
                *reinterpret_cast<unsigned*>(exWh + (s & 1) * PAR) = hw;
                *reinterpret_cast<unsigned*>(exWl + (s & 1) * PAR) = lw;
                if (s == 3)   // po write must precede this step's barrier
                    *reinterpret_cast<f32x4*>(&po[v * 4 + rg][cl][qt * 4]) = opv;
                __syncthreads();
                Bhi = *reinterpret_cast<const bf16x8*>(exRh + (s & 1) * PAR);
                Blo = *reinterpret_cast<const bf16x8*>(exRl + (s & 1) * PAR);
            }
            xq = xqn;
        }
    }

    // final chunk flush
    {
        int row = tid >> 4, seg = tid & 15;
        f32x4 sacc = {bout, bout, bout, bout};
#pragma unroll
        for (int g = 0; g < 16; ++g)
            sacc += *reinterpret_cast<const f32x4*>(&po[g][row][seg * 4]);
        *reinterpret_cast<f32x4*>(
            &outp[(size_t)(b0 + row) * T_LEN + (NCHUNK - 1) * CT + seg * 4]) = sacc;
    }

    // h_last at d_out[B*T + b*32 + j] (2 own units per lane)
#pragma unroll
    for (int u = 0; u < 2; ++u)
        outp[(size_t)BATCH * T_LEN + (size_t)(b0 + cl) * HID
             + 16 * half + 4 * rg + 2 * sub + u] = h2[u];
}

extern "C" void kernel_launch(void* const* d_in, const int* in_sizes, int n_in,
                              void* d_out, int out_size, void* d_ws, size_t ws_size,
                              hipStream_t stream) {
    const float* x     = (const float*)d_in[0];
    const float* h0    = (const float*)d_in[1];
    const float* Wih   = (const float*)d_in[2];
    const float* Whh   = (const float*)d_in[3];
    const float* bihv  = (const float*)d_in[4];
    const float* bhhv  = (const float*)d_in[5];
    const float* Woutv = (const float*)d_in[6];
    const float* boutv = (const float*)d_in[7];
    float* out = (float*)d_out;

    gru_fused7<<<dim3(BATCH / 16), dim3(256), 0, stream>>>(
        x, h0, Wih, Whh, bihv, bhhv, Woutv, boutv, out);
}